// Round 17
// baseline (343.634 us; speedup 1.0000x reference)
//
#include <hip/hip_runtime.h>

// GCN: x1 = relu(Agg(x@W1)+b1); x2 = relu(Agg(x1@W2)+b2); out = [x1,x2]@linW + linb
// Agg via CSR (counting sort) + gather-reduce; h stored bf16.
// GEMMs: plain bf16 MFMA. R17: agg is channel-phase-blocked (4 phases x 32ch):
// per-phase gather footprint = 3.2 MB slice of h < 4 MB L2/XCD -> random
// gathers become L2 hits (agg was L3-latency-bound at 15% VALU). Same
// instruction count & bytes (4 edges/wave-instr x 16-lane slots, 1 line/edge).

#define D128 128
#define NPHASE 4

typedef __attribute__((ext_vector_type(8))) short bf16x8;
typedef __attribute__((ext_vector_type(4))) float f32x4;

__device__ __forceinline__ unsigned short f2bf_bits(float v) {
    unsigned int u = __float_as_uint(v);
    unsigned int r = u + 0x7FFFu + ((u >> 16) & 1u);   // RNE
    return (unsigned short)(r >> 16);
}
__device__ __forceinline__ float bflo(unsigned int u) { return __uint_as_float(u << 16); }
__device__ __forceinline__ float bfhi(unsigned int u) { return __uint_as_float(u & 0xFFFF0000u); }

// ---------- degree count: 4 edges/thread ----------
__global__ void k_count(const int* __restrict__ dst, int* __restrict__ indeg, int E) {
    int base = (blockIdx.x * 256 + threadIdx.x) * 4;
    if (base + 3 < E) {
        int4 d = *(const int4*)&dst[base];
        atomicAdd(&indeg[d.x], 1);
        atomicAdd(&indeg[d.y], 1);
        atomicAdd(&indeg[d.z], 1);
        atomicAdd(&indeg[d.w], 1);
    } else {
        for (int e = base; e < E; ++e) atomicAdd(&indeg[dst[e]], 1);
    }
}

// ---------- scan1: block-local exclusive scan + dinv ----------
__global__ void k_scan1(const int* __restrict__ indeg, int* __restrict__ row_ptr,
                        int* __restrict__ bsum, float* __restrict__ dinv, int n) {
    __shared__ int tmp[256];
    int i = blockIdx.x * 256 + threadIdx.x;
    int v = (i < n) ? indeg[i] : 0;
    if (i < n) dinv[i] = rsqrtf((float)(v + 1));  // +1 self loop
    tmp[threadIdx.x] = v;
    __syncthreads();
    for (int off = 1; off < 256; off <<= 1) {
        int t = (threadIdx.x >= off) ? tmp[threadIdx.x - off] : 0;
        __syncthreads();
        tmp[threadIdx.x] += t;
        __syncthreads();
    }
    if (i < n) row_ptr[i] = tmp[threadIdx.x] - v;
    if (threadIdx.x == 255) bsum[blockIdx.x] = tmp[255];
}

// ---------- scan23: every block redundantly scans bsum, applies offset ----------
__global__ void k_scan23(int* __restrict__ row_ptr, const int* __restrict__ bsum,
                         int* __restrict__ cursor, int n, int E, int nb) {
    __shared__ int tmp[256];
    __shared__ int exc[256];
    int t = threadIdx.x;
    int v = (t < nb) ? bsum[t] : 0;
    tmp[t] = v;
    __syncthreads();
    for (int off = 1; off < 256; off <<= 1) {
        int x = (t >= off) ? tmp[t - off] : 0;
        __syncthreads();
        tmp[t] += x;
        __syncthreads();
    }
    exc[t] = tmp[t] - v;
    __syncthreads();
    int add = exc[blockIdx.x];
    int i = blockIdx.x * 256 + t;
    if (i < n) {
        int r = row_ptr[i] + add;
        row_ptr[i] = r;
        cursor[i] = r;
    }
    if (blockIdx.x == 0 && t == 0) row_ptr[n] = E;
}

// ---------- channel-phase-blocked aggregate + bias + relu ----------
// blockIdx = phase*ngroups + group; wave = 1 node; 16-lane slots = 4 edges
// per instruction, each lane 1 uint (2ch) of the phase's 16-uint slice.
// out = dv*( sum_e dinv[s]*h[s] + dv*h[node] ) + b, relu.
__global__ __launch_bounds__(256) void k_agg_phase(
    const unsigned int* __restrict__ h, const int* __restrict__ row_ptr,
    const int* __restrict__ csr_src, const float* __restrict__ dinv,
    const float* __restrict__ bias, float* __restrict__ o, int n, int ngroups)
{
    int phase = blockIdx.x / ngroups;
    int grp   = blockIdx.x % ngroups;
    int node  = grp * 4 + (threadIdx.x >> 6);
    if (node >= n) return;
    int lane = threadIdx.x & 63;
    int slot = lane >> 4;            // edge slot 0..3
    int ci   = lane & 15;            // uint within the 16-uint slice
    int hoff = phase * 16 + ci;

    float ax = 0.f, ay = 0.f;
    int j = row_ptr[node], end = row_ptr[node + 1];
    for (; j + 15 < end; j += 16) {          // 16 edges in flight per wave
        int s0 = csr_src[j + slot];
        int s1 = csr_src[j + 4 + slot];
        int s2 = csr_src[j + 8 + slot];
        int s3 = csr_src[j + 12 + slot];
        float d0 = dinv[s0], d1 = dinv[s1], d2 = dinv[s2], d3 = dinv[s3];
        unsigned int u0 = h[(size_t)s0 * 64 + hoff];
        unsigned int u1 = h[(size_t)s1 * 64 + hoff];
        unsigned int u2 = h[(size_t)s2 * 64 + hoff];
        unsigned int u3 = h[(size_t)s3 * 64 + hoff];
        ax += d0*bflo(u0) + d1*bflo(u1) + d2*bflo(u2) + d3*bflo(u3);
        ay += d0*bfhi(u0) + d1*bfhi(u1) + d2*bfhi(u2) + d3*bfhi(u3);
    }
    for (; j < end; j += 4) {                // masked 4-edge tail
        int e = j + slot;
        int ee = (e < end) ? e : (end - 1);
        int s = csr_src[ee];
        float d = (e < end) ? dinv[s] : 0.f;
        unsigned int u = h[(size_t)s * 64 + hoff];
        ax += d * bflo(u);
        ay += d * bfhi(u);
    }

    // sum the 4 edge slots (lanes l, l^16, l^32, l^48)
    ax += __shfl_xor(ax, 16); ay += __shfl_xor(ay, 16);
    ax += __shfl_xor(ax, 32); ay += __shfl_xor(ay, 32);

    if (slot == 0) {
        float dv = dinv[node];
        unsigned int su = h[(size_t)node * 64 + hoff];
        ax += dv * bflo(su);
        ay += dv * bfhi(su);
        float2 bv = ((const float2*)bias)[hoff];
        float2 ov = {fmaxf(dv * ax + bv.x, 0.f), fmaxf(dv * ay + bv.y, 0.f)};
        ((float2*)o)[(size_t)node * 64 + hoff] = ov;
    }
}

// ---------- MFMA GEMM building blocks (plain bf16, layouts R10-verified) ----------
__device__ __forceinline__ void stage_A_tile(
    const float* __restrict__ A, int brow, int n, int tid,
    unsigned short* __restrict__ Ah)
{
    const float4* A4 = (const float4*)(A + (size_t)brow * D128);
#pragma unroll
    for (int it = 0; it < 8; ++it) {
        int f = it * 256 + tid;
        int r = f >> 5, k4 = f & 31;
        float4 v = make_float4(0.f, 0.f, 0.f, 0.f);
        if (brow + r < n) v = A4[f];
        int lane_ = (r & 15) + 16 * ((k4 >> 1) & 3);
        int base = ((((k4 >> 3) * 4 + (r >> 4)) * 64 + lane_) << 3) + (k4 & 1) * 4;
        ushort4 hh;
        unsigned short* hp = (unsigned short*)&hh;
        hp[0] = f2bf_bits(v.x); hp[1] = f2bf_bits(v.y);
        hp[2] = f2bf_bits(v.z); hp[3] = f2bf_bits(v.w);
        *(ushort4*)&Ah[base] = hh;
    }
}

__device__ __forceinline__ void load_W_s(
    const float* __restrict__ W, int s, int colbase, int lanen, int kb,
    bf16x8 wh[2])
{
#pragma unroll
    for (int t = 0; t < 2; ++t)
#pragma unroll
        for (int j = 0; j < 8; ++j)
            wh[t][j] = (short)f2bf_bits(W[(size_t)(s * 32 + kb + j) * D128 + colbase + t * 16 + lanen]);
}

__device__ __forceinline__ void epilogue(
    f32x4 acc[4][2], float* __restrict__ C, const float* __restrict__ bias,
    int brow, int n, int colbase, int lanen, int l, int out_bf, int addC)
{
    float bv[2] = {0.f, 0.f};
    if (bias) { bv[0] = bias[colbase + lanen]; bv[1] = bias[colbase + 16 + lanen]; }
    int rsub = (l >> 4) * 4;
    if (out_bf) {
        unsigned short* Cb = (unsigned short*)C;
#pragma unroll
        for (int m = 0; m < 4; ++m)
#pragma unroll
            for (int t = 0; t < 2; ++t)
#pragma unroll
                for (int r = 0; r < 4; ++r) {
                    int row = brow + m * 16 + rsub + r;
                    if (row < n)
                        Cb[(size_t)row * D128 + colbase + t * 16 + lanen] = f2bf_bits(acc[m][t][r]);
                }
    } else {
#pragma unroll
        for (int m = 0; m < 4; ++m)
#pragma unroll
            for (int t = 0; t < 2; ++t)
#pragma unroll
                for (int r = 0; r < 4; ++r) {
                    int row = brow + m * 16 + rsub + r;
                    if (row < n) {
                        size_t idx = (size_t)row * D128 + colbase + t * 16 + lanen;
                        float v = acc[m][t][r] + bv[t];
                        if (addC) v += C[idx];
                        C[idx] = v;
                    }
                }
    }
}

__device__ __forceinline__ void gemm_core(
    const float* __restrict__ A, const float* __restrict__ W,
    const float* __restrict__ bias, float* __restrict__ C,
    int n, int out_bf, int addC, int bid, int tid,
    unsigned short* __restrict__ Ah)
{
    int l = tid & 63;
    int wv = tid >> 6;
    int brow = bid * 64;
    int colbase = wv * 32;
    int lanen = l & 15;
    int kb = (l >> 4) * 8;

    f32x4 acc[4][2];
#pragma unroll
    for (int m = 0; m < 4; ++m)
#pragma unroll
        for (int t = 0; t < 2; ++t) acc[m][t] = (f32x4){0.f, 0.f, 0.f, 0.f};

    stage_A_tile(A, brow, n, tid, Ah);
    __syncthreads();

#pragma unroll
    for (int s = 0; s < 4; ++s) {
        bf16x8 wh[2];
        load_W_s(W, s, colbase, lanen, kb, wh);
#pragma unroll
        for (int m = 0; m < 4; ++m) {
            bf16x8 ah = *(const bf16x8*)&Ah[((s * 4 + m) * 64 + l) * 8];
#pragma unroll
            for (int t = 0; t < 2; ++t)
                acc[m][t] = __builtin_amdgcn_mfma_f32_16x16x32_bf16(ah, wh[t], acc[m][t], 0, 0, 0);
        }
    }
    epilogue(acc, C, bias, brow, n, colbase, lanen, l, out_bf, addC);
}

// ---------- fused: gemm1 (blocks < gemmBlocks) + CSR fill (src-only scatter) ----------
__global__ __launch_bounds__(256, 2) void k_gemm1_fill(
    const float* __restrict__ x, const float* __restrict__ W1,
    float* __restrict__ h, int n,
    const int* __restrict__ src, const int* __restrict__ dst,
    int* __restrict__ cursor, int* __restrict__ csr_src,
    int E, int gemmBlocks)
{
    __shared__ unsigned short Ah[4 * 4 * 64 * 8];   // 16 KB
    if (blockIdx.x < gemmBlocks) {
        gemm_core(x, W1, nullptr, h, n, 1, 0, blockIdx.x, threadIdx.x, Ah);
    } else {
        int e = (blockIdx.x - gemmBlocks) * 256 + threadIdx.x;
        if (e >= E) return;
        int s = src[e], d = dst[e];
        int pos = atomicAdd(&cursor[d], 1);
        csr_src[pos] = s;
    }
}

// ---------- standalone single-source gemm (gemm3b) ----------
__global__ __launch_bounds__(256, 2) void k_gemm_mfma(
    const float* __restrict__ A, const float* __restrict__ W,
    const float* __restrict__ bias, float* __restrict__ C,
    int n, int out_bf, int addC)
{
    __shared__ unsigned short Ah[4 * 4 * 64 * 8];
    gemm_core(A, W, bias, C, n, out_bf, addC, blockIdx.x, threadIdx.x, Ah);
}

// ---------- dual: h2 = bf16(x1@W2), p = x1@linW_top (one A staging) ----------
__global__ __launch_bounds__(256, 2) void k_gemm_dual(
    const float* __restrict__ A, const float* __restrict__ W2,
    const float* __restrict__ Wtop, float* __restrict__ hOut,
    float* __restrict__ pOut, int n)
{
    __shared__ unsigned short Ah[4 * 4 * 64 * 8];
    int tid = threadIdx.x;
    int l = tid & 63;
    int wv = tid >> 6;
    int brow = blockIdx.x * 64;
    int colbase = wv * 32;
    int lanen = l & 15;
    int kb = (l >> 4) * 8;

    f32x4 accA[4][2], accB[4][2];
#pragma unroll
    for (int m = 0; m < 4; ++m)
#pragma unroll
        for (int t = 0; t < 2; ++t) {
            accA[m][t] = (f32x4){0.f, 0.f, 0.f, 0.f};
            accB[m][t] = (f32x4){0.f, 0.f, 0.f, 0.f};
        }

    stage_A_tile(A, brow, n, tid, Ah);
    __syncthreads();

#pragma unroll
    for (int s = 0; s < 4; ++s) {
        bf16x8 whA[2], whB[2];
        load_W_s(W2, s, colbase, lanen, kb, whA);
        load_W_s(Wtop, s, colbase, lanen, kb, whB);
#pragma unroll
        for (int m = 0; m < 4; ++m) {
            bf16x8 ah = *(const bf16x8*)&Ah[((s * 4 + m) * 64 + l) * 8];
#pragma unroll
            for (int t = 0; t < 2; ++t) {
                accA[m][t] = __builtin_amdgcn_mfma_f32_16x16x32_bf16(ah, whA[t], accA[m][t], 0, 0, 0);
                accB[m][t] = __builtin_amdgcn_mfma_f32_16x16x32_bf16(ah, whB[t], accB[m][t], 0, 0, 0);
            }
        }
    }
    epilogue(accA, hOut, nullptr, brow, n, colbase, lanen, l, 1, 0);
    epilogue(accB, pOut, nullptr, brow, n, colbase, lanen, l, 0, 0);
}

extern "C" void kernel_launch(void* const* d_in, const int* in_sizes, int n_in,
                              void* d_out, int out_size, void* d_ws, size_t ws_size,
                              hipStream_t stream) {
    const float* x    = (const float*)d_in[0];
    const int*   ei   = (const int*)d_in[1];
    const float* W1   = (const float*)d_in[2];
    const float* b1   = (const float*)d_in[3];
    const float* W2   = (const float*)d_in[4];
    const float* b2   = (const float*)d_in[5];
    const float* linW = (const float*)d_in[6];
    const float* linb = (const float*)d_in[7];

    int n = in_sizes[0] / D128;
    int E = in_sizes[1] / 2;
    const int* src = ei;
    const int* dst = ei + E;

    float* out = (float*)d_out;
    float* ws  = (float*)d_ws;

    // ws (4B words): csr_src[E] | indeg[n] | dinv[n] | row_ptr[n+1] | bsum[256]
    //                | cursor[n] | align | x1[n*128] | x2[n*128] | h[n*64 uints]
    size_t o = 0;
    int*   csr_src = (int*)(ws + o);    o += E;
    int*   indeg   = (int*)(ws + o);    o += n;
    float* dinv    = ws + o;            o += n;
    int*   row_ptr = (int*)(ws + o);    o += n + 1;
    int*   bsum    = (int*)(ws + o);    o += 256;
    int*   cursor  = (int*)(ws + o);    o += n;
    o = (o + 3) & ~(size_t)3;
    float* x1      = ws + o;            o += (size_t)n * D128;
    float* x2      = ws + o;            o += (size_t)n * D128;
    float* h       = ws + o;            // bf16-packed, n*64 uints

    int gn = (n + 255) / 256;
    int gE  = (E + 255) / 256;          // fill: 1 edge/thread
    int gE4 = (E + 1023) / 1024;        // count: 4 edges/thread
    int gemmBlocks = (n + 63) / 64;
    int ngroups = (n + 3) / 4;          // 4 nodes per block per phase
    int aggBlocks = NPHASE * ngroups;

    // CSR prep
    (void)hipMemsetAsync(indeg, 0, (size_t)n * sizeof(int), stream);
    k_count<<<gE4, 256, 0, stream>>>(dst, indeg, E);
    k_scan1<<<gn, 256, 0, stream>>>(indeg, row_ptr, bsum, dinv, n);
    k_scan23<<<gn, 256, 0, stream>>>(row_ptr, bsum, cursor, n, E, gn);

    // gemm1 (h = bf16(x@W1)) fused with CSR fill
    k_gemm1_fill<<<gemmBlocks + gE, 256, 0, stream>>>(
        x, W1, h, n, src, dst, cursor, csr_src, E, gemmBlocks);

    // layer 1 aggregate (channel-phase-blocked)
    k_agg_phase<<<aggBlocks, 256, 0, stream>>>((const unsigned int*)h, row_ptr, csr_src, dinv, b1, x1, n, ngroups);

    // layer 2 gemm + first half of final linear (shared A staging)
    k_gemm_dual<<<gemmBlocks, 256, 0, stream>>>(x1, W2, linW, h, out, n);

    // layer 2 aggregate
    k_agg_phase<<<aggBlocks, 256, 0, stream>>>((const unsigned int*)h, row_ptr, csr_src, dinv, b2, x2, n, ngroups);

    // final: out += x2 @ linW[128:256] + linb
    k_gemm_mfma<<<gemmBlocks, 256, 0, stream>>>(x2, linW + 128 * D128, linb, out, n, 0, 1);
}

// Round 18
// 224.464 us; speedup vs baseline: 1.5309x; 1.5309x over previous
//
#include <hip/hip_runtime.h>

// GCN: x1 = relu(Agg(x@W1)+b1); x2 = relu(Agg(x1@W2)+b2); out = [x1,x2]@linW + linb
// Agg via CSR (counting sort) + per-node wave gather-reduce (R12 structure —
// its ~43us is the measured floor; R13/R14/R17 restructures all regressed).
// h, x1, x2 all stored packed bf16 (threshold 1.5e-2 = 8x bf16-eps).
// GEMMs: plain bf16 MFMA; dual kernel shares one A-staging for W2 + linW_top.

#define D128 128

typedef __attribute__((ext_vector_type(8))) short bf16x8;
typedef __attribute__((ext_vector_type(4))) float f32x4;

__device__ __forceinline__ unsigned short f2bf_bits(float v) {
    unsigned int u = __float_as_uint(v);
    unsigned int r = u + 0x7FFFu + ((u >> 16) & 1u);   // RNE
    return (unsigned short)(r >> 16);
}
__device__ __forceinline__ float bflo(unsigned int u) { return __uint_as_float(u << 16); }
__device__ __forceinline__ float bfhi(unsigned int u) { return __uint_as_float(u & 0xFFFF0000u); }

// ---------- degree count: 4 edges/thread ----------
__global__ void k_count(const int* __restrict__ dst, int* __restrict__ indeg, int E) {
    int base = (blockIdx.x * 256 + threadIdx.x) * 4;
    if (base + 3 < E) {
        int4 d = *(const int4*)&dst[base];
        atomicAdd(&indeg[d.x], 1);
        atomicAdd(&indeg[d.y], 1);
        atomicAdd(&indeg[d.z], 1);
        atomicAdd(&indeg[d.w], 1);
    } else {
        for (int e = base; e < E; ++e) atomicAdd(&indeg[dst[e]], 1);
    }
}

// ---------- scan1: block-local exclusive scan + dinv ----------
__global__ void k_scan1(const int* __restrict__ indeg, int* __restrict__ row_ptr,
                        int* __restrict__ bsum, float* __restrict__ dinv, int n) {
    __shared__ int tmp[256];
    int i = blockIdx.x * 256 + threadIdx.x;
    int v = (i < n) ? indeg[i] : 0;
    if (i < n) dinv[i] = rsqrtf((float)(v + 1));  // +1 self loop
    tmp[threadIdx.x] = v;
    __syncthreads();
    for (int off = 1; off < 256; off <<= 1) {
        int t = (threadIdx.x >= off) ? tmp[threadIdx.x - off] : 0;
        __syncthreads();
        tmp[threadIdx.x] += t;
        __syncthreads();
    }
    if (i < n) row_ptr[i] = tmp[threadIdx.x] - v;
    if (threadIdx.x == 255) bsum[blockIdx.x] = tmp[255];
}

// ---------- scan23: every block redundantly scans bsum, applies offset ----------
__global__ void k_scan23(int* __restrict__ row_ptr, const int* __restrict__ bsum,
                         int* __restrict__ cursor, int n, int E, int nb) {
    __shared__ int tmp[256];
    __shared__ int exc[256];
    int t = threadIdx.x;
    int v = (t < nb) ? bsum[t] : 0;
    tmp[t] = v;
    __syncthreads();
    for (int off = 1; off < 256; off <<= 1) {
        int x = (t >= off) ? tmp[t - off] : 0;
        __syncthreads();
        tmp[t] += x;
        __syncthreads();
    }
    exc[t] = tmp[t] - v;
    __syncthreads();
    int add = exc[blockIdx.x];
    int i = blockIdx.x * 256 + t;
    if (i < n) {
        int r = row_ptr[i] + add;
        row_ptr[i] = r;
        cursor[i] = r;
    }
    if (blockIdx.x == 0 && t == 0) row_ptr[n] = E;
}

// ---------- aggregate + bias + relu ; h packed bf16x2; OUT packed bf16x2 ----------
// out = bf16( relu( dv*( sum_e dinv[s]*h[s] + dv*h[node] ) + b ) )
__global__ __launch_bounds__(256) void k_agg_csr(
    const unsigned int* __restrict__ h, const int* __restrict__ row_ptr,
    const int* __restrict__ csr_src, const float* __restrict__ dinv,
    const float* __restrict__ bias, unsigned int* __restrict__ o, int n)
{
    int node = blockIdx.x * 4 + (threadIdx.x >> 6);
    int lane = threadIdx.x & 63;
    if (node >= n) return;
    float dv = dinv[node];
    unsigned int su = h[node * 64 + lane];
    float ax = dv * bflo(su);           // self term, outer dv applied at end
    float ay = dv * bfhi(su);
    int j = row_ptr[node], end = row_ptr[node + 1];
    for (; j + 7 < end; j += 8) {
        int s0 = csr_src[j+0], s1 = csr_src[j+1], s2 = csr_src[j+2], s3 = csr_src[j+3];
        int s4 = csr_src[j+4], s5 = csr_src[j+5], s6 = csr_src[j+6], s7 = csr_src[j+7];
        float d0 = dinv[s0], d1 = dinv[s1], d2 = dinv[s2], d3 = dinv[s3];
        float d4 = dinv[s4], d5 = dinv[s5], d6 = dinv[s6], d7 = dinv[s7];
        unsigned int u0 = h[s0 * 64 + lane];
        unsigned int u1 = h[s1 * 64 + lane];
        unsigned int u2 = h[s2 * 64 + lane];
        unsigned int u3 = h[s3 * 64 + lane];
        unsigned int u4 = h[s4 * 64 + lane];
        unsigned int u5 = h[s5 * 64 + lane];
        unsigned int u6 = h[s6 * 64 + lane];
        unsigned int u7 = h[s7 * 64 + lane];
        ax += d0*bflo(u0) + d1*bflo(u1) + d2*bflo(u2) + d3*bflo(u3)
            + d4*bflo(u4) + d5*bflo(u5) + d6*bflo(u6) + d7*bflo(u7);
        ay += d0*bfhi(u0) + d1*bfhi(u1) + d2*bfhi(u2) + d3*bfhi(u3)
            + d4*bfhi(u4) + d5*bfhi(u5) + d6*bfhi(u6) + d7*bfhi(u7);
    }
    for (; j + 3 < end; j += 4) {
        int s0 = csr_src[j+0], s1 = csr_src[j+1], s2 = csr_src[j+2], s3 = csr_src[j+3];
        float d0 = dinv[s0], d1 = dinv[s1], d2 = dinv[s2], d3 = dinv[s3];
        unsigned int u0 = h[s0 * 64 + lane];
        unsigned int u1 = h[s1 * 64 + lane];
        unsigned int u2 = h[s2 * 64 + lane];
        unsigned int u3 = h[s3 * 64 + lane];
        ax += d0*bflo(u0) + d1*bflo(u1) + d2*bflo(u2) + d3*bflo(u3);
        ay += d0*bfhi(u0) + d1*bfhi(u1) + d2*bfhi(u2) + d3*bfhi(u3);
    }
    for (; j < end; ++j) {
        int s = csr_src[j];
        float d = dinv[s];
        unsigned int u = h[s * 64 + lane];
        ax += d * bflo(u);
        ay += d * bfhi(u);
    }
    float2 bv = ((const float2*)bias)[lane];
    unsigned int lo = f2bf_bits(fmaxf(dv * ax + bv.x, 0.f));
    unsigned int hi = f2bf_bits(fmaxf(dv * ay + bv.y, 0.f));
    o[node * 64 + lane] = lo | (hi << 16);
}

// ---------- MFMA GEMM building blocks (plain bf16, layouts R10-verified) ----------
// A-frag LDS order: [s 4][m 4][lane 64][j 8]; lane_=(r&15)+16*((k4>>1)&3).
__device__ __forceinline__ void stage_A_tile_f32(
    const float* __restrict__ A, int brow, int n, int tid,
    unsigned short* __restrict__ Ah)
{
    const float4* A4 = (const float4*)(A + (size_t)brow * D128);
#pragma unroll
    for (int it = 0; it < 8; ++it) {
        int f = it * 256 + tid;
        int r = f >> 5, k4 = f & 31;
        float4 v = make_float4(0.f, 0.f, 0.f, 0.f);
        if (brow + r < n) v = A4[f];
        int lane_ = (r & 15) + 16 * ((k4 >> 1) & 3);
        int base = ((((k4 >> 3) * 4 + (r >> 4)) * 64 + lane_) << 3) + (k4 & 1) * 4;
        ushort4 hh;
        unsigned short* hp = (unsigned short*)&hh;
        hp[0] = f2bf_bits(v.x); hp[1] = f2bf_bits(v.y);
        hp[2] = f2bf_bits(v.z); hp[3] = f2bf_bits(v.w);
        *(ushort4*)&Ah[base] = hh;
    }
}

// A already packed bf16 (row stride 128 ushorts): straight copy, no convert.
__device__ __forceinline__ void stage_A_tile_bf16(
    const unsigned short* __restrict__ A, int brow, int n, int tid,
    unsigned short* __restrict__ Ah)
{
    const ushort4* A4 = (const ushort4*)(A + (size_t)brow * D128);
#pragma unroll
    for (int it = 0; it < 8; ++it) {
        int f = it * 256 + tid;
        int r = f >> 5, k4 = f & 31;
        ushort4 v = make_ushort4(0, 0, 0, 0);
        if (brow + r < n) v = A4[f];
        int lane_ = (r & 15) + 16 * ((k4 >> 1) & 3);
        int base = ((((k4 >> 3) * 4 + (r >> 4)) * 64 + lane_) << 3) + (k4 & 1) * 4;
        *(ushort4*)&Ah[base] = v;
    }
}

__device__ __forceinline__ void load_W_s(
    const float* __restrict__ W, int s, int colbase, int lanen, int kb,
    bf16x8 wh[2])
{
#pragma unroll
    for (int t = 0; t < 2; ++t)
#pragma unroll
        for (int j = 0; j < 8; ++j)
            wh[t][j] = (short)f2bf_bits(W[(size_t)(s * 32 + kb + j) * D128 + colbase + t * 16 + lanen]);
}

__device__ __forceinline__ void epilogue(
    f32x4 acc[4][2], float* __restrict__ C, const float* __restrict__ bias,
    int brow, int n, int colbase, int lanen, int l, int out_bf, int addC)
{
    float bv[2] = {0.f, 0.f};
    if (bias) { bv[0] = bias[colbase + lanen]; bv[1] = bias[colbase + 16 + lanen]; }
    int rsub = (l >> 4) * 4;
    if (out_bf) {
        unsigned short* Cb = (unsigned short*)C;
#pragma unroll
        for (int m = 0; m < 4; ++m)
#pragma unroll
            for (int t = 0; t < 2; ++t)
#pragma unroll
                for (int r = 0; r < 4; ++r) {
                    int row = brow + m * 16 + rsub + r;
                    if (row < n)
                        Cb[(size_t)row * D128 + colbase + t * 16 + lanen] = f2bf_bits(acc[m][t][r]);
                }
    } else {
#pragma unroll
        for (int m = 0; m < 4; ++m)
#pragma unroll
            for (int t = 0; t < 2; ++t)
#pragma unroll
                for (int r = 0; r < 4; ++r) {
                    int row = brow + m * 16 + rsub + r;
                    if (row < n) {
                        size_t idx = (size_t)row * D128 + colbase + t * 16 + lanen;
                        float v = acc[m][t][r] + bv[t];
                        if (addC) v += C[idx];
                        C[idx] = v;
                    }
                }
    }
}

__device__ __forceinline__ void gemm_compute(
    const float* __restrict__ W, f32x4 acc[4][2],
    int colbase, int lanen, int kb, int l,
    const unsigned short* __restrict__ Ah)
{
#pragma unroll
    for (int s = 0; s < 4; ++s) {
        bf16x8 wh[2];
        load_W_s(W, s, colbase, lanen, kb, wh);
#pragma unroll
        for (int m = 0; m < 4; ++m) {
            bf16x8 ah = *(const bf16x8*)&Ah[((s * 4 + m) * 64 + l) * 8];
#pragma unroll
            for (int t = 0; t < 2; ++t)
                acc[m][t] = __builtin_amdgcn_mfma_f32_16x16x32_bf16(ah, wh[t], acc[m][t], 0, 0, 0);
        }
    }
}

// ---------- fused: gemm1 (fp32 A; blocks < gemmBlocks) + CSR fill ----------
__global__ __launch_bounds__(256, 2) void k_gemm1_fill(
    const float* __restrict__ x, const float* __restrict__ W1,
    float* __restrict__ h, int n,
    const int* __restrict__ src, const int* __restrict__ dst,
    int* __restrict__ cursor, int* __restrict__ csr_src,
    int E, int gemmBlocks)
{
    __shared__ unsigned short Ah[4 * 4 * 64 * 8];   // 16 KB
    if (blockIdx.x < gemmBlocks) {
        int tid = threadIdx.x;
        int l = tid & 63, wv = tid >> 6;
        int brow = blockIdx.x * 64;
        int colbase = wv * 32, lanen = l & 15, kb = (l >> 4) * 8;
        f32x4 acc[4][2];
#pragma unroll
        for (int m = 0; m < 4; ++m)
#pragma unroll
            for (int t = 0; t < 2; ++t) acc[m][t] = (f32x4){0.f, 0.f, 0.f, 0.f};
        stage_A_tile_f32(x, brow, n, tid, Ah);
        __syncthreads();
        gemm_compute(W1, acc, colbase, lanen, kb, l, Ah);
        epilogue(acc, h, nullptr, brow, n, colbase, lanen, l, 1, 0);
    } else {
        int e = (blockIdx.x - gemmBlocks) * 256 + threadIdx.x;
        if (e >= E) return;
        int s = src[e], d = dst[e];
        int pos = atomicAdd(&cursor[d], 1);
        csr_src[pos] = s;
    }
}

// ---------- gemm3b: A = bf16 x2; out += x2@linW_bot + bias (fp32 accumulate) ----------
__global__ __launch_bounds__(256, 2) void k_gemm_bf16A(
    const unsigned short* __restrict__ A, const float* __restrict__ W,
    const float* __restrict__ bias, float* __restrict__ C, int n)
{
    __shared__ unsigned short Ah[4 * 4 * 64 * 8];
    int tid = threadIdx.x;
    int l = tid & 63, wv = tid >> 6;
    int brow = blockIdx.x * 64;
    int colbase = wv * 32, lanen = l & 15, kb = (l >> 4) * 8;
    f32x4 acc[4][2];
#pragma unroll
    for (int m = 0; m < 4; ++m)
#pragma unroll
        for (int t = 0; t < 2; ++t) acc[m][t] = (f32x4){0.f, 0.f, 0.f, 0.f};
    stage_A_tile_bf16(A, brow, n, tid, Ah);
    __syncthreads();
    gemm_compute(W, acc, colbase, lanen, kb, l, Ah);
    epilogue(acc, C, bias, brow, n, colbase, lanen, l, 0, 1);
}

// ---------- dual: A = bf16 x1; h2 = bf16(x1@W2), p = x1@linW_top (fp32) ----------
__global__ __launch_bounds__(256, 2) void k_gemm_dual(
    const unsigned short* __restrict__ A, const float* __restrict__ W2,
    const float* __restrict__ Wtop, float* __restrict__ hOut,
    float* __restrict__ pOut, int n)
{
    __shared__ unsigned short Ah[4 * 4 * 64 * 8];
    int tid = threadIdx.x;
    int l = tid & 63, wv = tid >> 6;
    int brow = blockIdx.x * 64;
    int colbase = wv * 32, lanen = l & 15, kb = (l >> 4) * 8;

    f32x4 accA[4][2], accB[4][2];
#pragma unroll
    for (int m = 0; m < 4; ++m)
#pragma unroll
        for (int t = 0; t < 2; ++t) {
            accA[m][t] = (f32x4){0.f, 0.f, 0.f, 0.f};
            accB[m][t] = (f32x4){0.f, 0.f, 0.f, 0.f};
        }

    stage_A_tile_bf16(A, brow, n, tid, Ah);
    __syncthreads();

#pragma unroll
    for (int s = 0; s < 4; ++s) {
        bf16x8 whA[2], whB[2];
        load_W_s(W2, s, colbase, lanen, kb, whA);
        load_W_s(Wtop, s, colbase, lanen, kb, whB);
#pragma unroll
        for (int m = 0; m < 4; ++m) {
            bf16x8 ah = *(const bf16x8*)&Ah[((s * 4 + m) * 64 + l) * 8];
#pragma unroll
            for (int t = 0; t < 2; ++t) {
                accA[m][t] = __builtin_amdgcn_mfma_f32_16x16x32_bf16(ah, whA[t], accA[m][t], 0, 0, 0);
                accB[m][t] = __builtin_amdgcn_mfma_f32_16x16x32_bf16(ah, whB[t], accB[m][t], 0, 0, 0);
            }
        }
    }
    epilogue(accA, hOut, nullptr, brow, n, colbase, lanen, l, 1, 0);
    epilogue(accB, pOut, nullptr, brow, n, colbase, lanen, l, 0, 0);
}

extern "C" void kernel_launch(void* const* d_in, const int* in_sizes, int n_in,
                              void* d_out, int out_size, void* d_ws, size_t ws_size,
                              hipStream_t stream) {
    const float* x    = (const float*)d_in[0];
    const int*   ei   = (const int*)d_in[1];
    const float* W1   = (const float*)d_in[2];
    const float* b1   = (const float*)d_in[3];
    const float* W2   = (const float*)d_in[4];
    const float* b2   = (const float*)d_in[5];
    const float* linW = (const float*)d_in[6];
    const float* linb = (const float*)d_in[7];

    int n = in_sizes[0] / D128;
    int E = in_sizes[1] / 2;
    const int* src = ei;
    const int* dst = ei + E;

    float* out = (float*)d_out;
    float* ws  = (float*)d_ws;

    // ws (4B words): csr_src[E] | indeg[n] | dinv[n] | row_ptr[n+1] | bsum[256]
    //                | cursor[n] | align | x1[n*64] | x2[n*64] | h[n*64] (all bf16x2)
    size_t o = 0;
    int*   csr_src = (int*)(ws + o);    o += E;
    int*   indeg   = (int*)(ws + o);    o += n;
    float* dinv    = ws + o;            o += n;
    int*   row_ptr = (int*)(ws + o);    o += n + 1;
    int*   bsum    = (int*)(ws + o);    o += 256;
    int*   cursor  = (int*)(ws + o);    o += n;
    o = (o + 3) & ~(size_t)3;
    unsigned int* x1 = (unsigned int*)(ws + o);  o += (size_t)n * 64;
    unsigned int* x2 = (unsigned int*)(ws + o);  o += (size_t)n * 64;
    float* h         = ws + o;                   // bf16-packed, n*64 uints

    int gn = (n + 255) / 256;
    int gE  = (E + 255) / 256;          // fill: 1 edge/thread
    int gE4 = (E + 1023) / 1024;        // count: 4 edges/thread
    int gemmBlocks = (n + 63) / 64;
    int aggBlocks  = (n + 3) / 4;

    // CSR prep
    (void)hipMemsetAsync(indeg, 0, (size_t)n * sizeof(int), stream);
    k_count<<<gE4, 256, 0, stream>>>(dst, indeg, E);
    k_scan1<<<gn, 256, 0, stream>>>(indeg, row_ptr, bsum, dinv, n);
    k_scan23<<<gn, 256, 0, stream>>>(row_ptr, bsum, cursor, n, E, gn);

    // gemm1 (h = bf16(x@W1)) fused with CSR fill
    k_gemm1_fill<<<gemmBlocks + gE, 256, 0, stream>>>(
        x, W1, h, n, src, dst, cursor, csr_src, E, gemmBlocks);

    // layer 1 aggregate -> x1 (bf16)
    k_agg_csr<<<aggBlocks, 256, 0, stream>>>((const unsigned int*)h, row_ptr, csr_src, dinv, b1, x1, n);

    // layer 2 gemm + first half of final linear (A = bf16 x1)
    k_gemm_dual<<<gemmBlocks, 256, 0, stream>>>((const unsigned short*)x1, W2, linW, h, out, n);

    // layer 2 aggregate -> x2 (bf16)
    k_agg_csr<<<aggBlocks, 256, 0, stream>>>((const unsigned int*)h, row_ptr, csr_src, dinv, b2, x2, n);

    // final: out += x2 @ linW[128:256] + linb
    k_gemm_bf16A<<<gemmBlocks, 256, 0, stream>>>((const unsigned short*)x2, linW + 128 * D128, linb, out, n);
}